// Round 6
// baseline (1722.155 us; speedup 1.0000x reference)
//
#include <hip/hip_runtime.h>
#include <stdint.h>
#include <stddef.h>

// Variational-dropout LSTM, SEQ=256, B=64, IN=H=1024, fp32 I/O.
//
// R9: flag-free dataflow recurrence. mh_seq slots 1..256 are pre-filled with
// the sentinel 0xFFFF (bf16 NaN, unreachable by f2bf of finite h*mask).
// Producers fire atomic u64 write-through mh stores and move on (no drain,
// no flag, no LDS counter). Each consumer WAVE independently bypass-loads
// its 16 mh fragments and re-polls until sentinel-free (u64 atomicity =>
// checking one u16 per u64 suffices; each 16B fragment covers 2 u64s from
// 2 producer blocks). Removes ~2700cy of protocol from the step chain and
// the block-wide gate barrier (wave-granular dataflow). The prefetch is
// issued before the x-projection so the ~900cy MALL latency overlaps it.
// Geometry: R6's 256 blocks x 4 h-cols (proven fastest). Prep vectorized
// (short8 stores, grid 8192). R5/R7 lessons: no fences, no cached mh.
// Fallback (small ws): R3's per-step launch path, unchanged.

#define SEQ 256

typedef __attribute__((ext_vector_type(8))) __bf16 bf16x8;
typedef __attribute__((ext_vector_type(4))) float  f32x4;
typedef __attribute__((ext_vector_type(4))) _Float16 f16x4;
typedef __attribute__((ext_vector_type(4))) unsigned int u32x4;
typedef unsigned short u16;
typedef unsigned int   u32;
typedef unsigned long long u64;

__device__ __forceinline__ u16 f2bf(float f) {
  union { float f; unsigned u; } v; v.f = f;
  unsigned r = v.u + 0x7FFFu + ((v.u >> 16) & 1u);   // RNE
  return (u16)(r >> 16);
}
__device__ __forceinline__ float sigm(float x) {
  return __builtin_amdgcn_rcpf(1.f + __expf(-x));
}
__device__ __forceinline__ float tanh_fast(float x) {
  float xc = fminf(15.f, fmaxf(-15.f, x));
  float t = __expf(-2.f * xc);
  return (1.f - t) * __builtin_amdgcn_rcpf(1.f + t);
}
__device__ __forceinline__ float pick4(int idx, float v0, float v1, float v2, float v3) {
  float lo = (idx & 1) ? v1 : v0;
  float hi = (idx & 1) ? v3 : v2;
  return (idx & 2) ? hi : lo;
}

// ws layout (bytes):
//  Wihp  @ 0         : [bk 256][kcw 32][l 64][e 8] bf16 = 8388608
//  Whhp  @ 8388608   : same = 8388608
//  Ap    @ 16777216  : [s 256][m 4][kwg 32][l 64][e 8] bf16 = 33554432
//  mh0   @ 50331648  : [m 4][kwg 32][l 64][e 8] bf16 = 131072   (fallback)
//  mh1   @ 50462720  : 131072                                   (fallback)
//  bias  @ 50593792  : 4096 f32 = 16384
//  c     @ 50610176  : [b 64][col 1024] f32 = 262144            (fallback)
//  (gap) @ 50872320  : 1024 (old flags, unused)
//  mh_seq@ 50873344  : 257 x 131072 = 33685504   (end: 84558848)

// Vectorized prep: grid 8192 x 256, each thread handles 8 contiguous u16.
__global__ __launch_bounds__(256) void prep_kernel(
    const float* __restrict__ x, const float* __restrict__ h0,
    const float* __restrict__ c0, const float* __restrict__ mask_x,
    const float* __restrict__ mask_h, const float* __restrict__ Wih,
    const float* __restrict__ Whh, const float* __restrict__ bih,
    const float* __restrict__ bhh,
    u16* __restrict__ Wihp, u16* __restrict__ Whhp, u16* __restrict__ Ap,
    u16* __restrict__ mhp0, float* __restrict__ bias, float* __restrict__ c,
    u16* __restrict__ mh_seq, int persist)
{
  const unsigned t    = blockIdx.x * 256u + threadIdx.x;  // 0 .. 2097151
  const unsigned idx8 = t * 8u;

  union Pack8 { u16 o[8]; u32x4 v; };

  // Ap[s][m][kwg][l][e0..7] = bf16( x * mask_x ), 8 contiguous k per thread
  {
    const unsigned l   = (idx8 >> 3) & 63u;
    const unsigned kwg = (idx8 >> 9) & 31u;
    const unsigned m   = (idx8 >> 14) & 3u;
    const unsigned s   = idx8 >> 16;
    const unsigned b   = m * 16u + (l & 15u);
    const unsigned k   = kwg * 32u + (l >> 4) * 8u;
    const float* xp = &x[((size_t)s * 64u + b) * 1024u + k];
    const float* mp = &mask_x[b * 1024u + k];
    Pack8 p;
    #pragma unroll
    for (int e = 0; e < 8; ++e) p.o[e] = f2bf(xp[e] * mp[e]);
    *(u32x4*)&Ap[idx8] = p.v;
  }
  // Sentinel fill of mh_seq slots 1..256 (exactly 2097152*8 u16).
  if (persist) {
    u32x4 ones = {0xFFFFFFFFu, 0xFFFFFFFFu, 0xFFFFFFFFu, 0xFFFFFFFFu};
    *(u32x4*)&mh_seq[65536u + idx8] = ones;
  }
  // W swizzles: n = (nl&3)*1024 + wb*4 + (nl>>2), 8 contiguous k
  if (t < 524288u) {
    const unsigned l   = (idx8 >> 3) & 63u;
    const unsigned kcw = (idx8 >> 9) & 31u;
    const unsigned wb  = idx8 >> 14;
    const unsigned nl  = l & 15u;
    const unsigned n   = (nl & 3u) * 1024u + wb * 4u + (nl >> 2);
    const unsigned k   = kcw * 32u + (l >> 4) * 8u;
    const float* wip = &Wih[n * 1024u + k];
    const float* whp = &Whh[n * 1024u + k];
    Pack8 pi, ph;
    #pragma unroll
    for (int e = 0; e < 8; ++e) { pi.o[e] = f2bf(wip[e]); ph.o[e] = f2bf(whp[e]); }
    *(u32x4*)&Wihp[idx8] = pi.v;
    *(u32x4*)&Whhp[idx8] = ph.v;
  }
  // mh slot 0 = bf16(h0 * mask_h); c init (fallback path)
  if (t < 8192u) {
    const unsigned l   = (idx8 >> 3) & 63u;
    const unsigned kwg = (idx8 >> 9) & 31u;
    const unsigned m   = idx8 >> 14;
    const unsigned b   = m * 16u + (l & 15u);
    const unsigned k   = kwg * 32u + (l >> 4) * 8u;
    const float* hp = &h0[b * 1024u + k];
    const float* mp = &mask_h[b * 1024u + k];
    Pack8 p;
    #pragma unroll
    for (int e = 0; e < 8; ++e) p.o[e] = f2bf(hp[e] * mp[e]);
    *(u32x4*)&mhp0[idx8] = p.v;
    *(f32x4*)&c[idx8]     = *(const f32x4*)&c0[idx8];
    *(f32x4*)&c[idx8 + 4] = *(const f32x4*)&c0[idx8 + 4];
  }
  if (t < 512u) {
    #pragma unroll
    for (int e = 0; e < 8; ++e) bias[idx8 + e] = bih[idx8 + e] + bhh[idx8 + e];
  }
}

// ---------------------------------------------------------------------------
// Persistent recurrence kernel: 256 blocks x 512 threads, all 256 steps.
// Block bk owns h-cols [bk*4, bk*4+4). Wave w owns K-slice [w*128,(w+1)*128).
// No flags: each wave polls its own mh fragments for the 0xFFFF sentinel.
// ---------------------------------------------------------------------------
__global__ __launch_bounds__(512, 2) void lstm_persist(
    const u16* __restrict__ Ap, const u16* __restrict__ Wihp,
    const u16* __restrict__ Whhp, const float* __restrict__ bias,
    const float* __restrict__ c0, const float* __restrict__ mask_h,
    u16* __restrict__ mh_seq, float* __restrict__ out)
{
  __shared__ f32x4 lds[8][4][64];   // [w][m][l] 32 KB

  const int tid = threadIdx.x;
  const int w   = tid >> 6;       // K-slice 0..7
  const int l   = tid & 63;
  const int bk  = blockIdx.x;

  const bf16x8* WHV = (const bf16x8*)Whhp;
  const bf16x8* WIV = (const bf16x8*)Wihp;
  const bf16x8* ApV = (const bf16x8*)Ap;

  // Weights resident in registers for the whole sequence.
  bf16x8 wh[4], wi[4];
  #pragma unroll
  for (int kw = 0; kw < 4; ++kw) {
    wh[kw] = WHV[(bk * 32 + w * 4 + kw) * 64 + l];
    wi[kw] = WIV[(bk * 32 + w * 4 + kw) * 64 + l];
  }

  const int nl     = l & 15;
  const int quad   = l >> 4;
  const int g_role = nl & 3;
  const int jh     = nl >> 2;
  const int col_h  = bk * 4 + jh;

  // Cell state + per-lane constants in registers (epilogue waves only).
  float bias_reg = 0.f;
  float c_reg[4]    = {0.f, 0.f, 0.f, 0.f};
  float mask_reg[4] = {0.f, 0.f, 0.f, 0.f};
  if (w < 4) {
    bias_reg = bias[g_role * 1024 + col_h];
    #pragma unroll
    for (int r = 0; r < 4; ++r) {
      const int row = w * 16 + quad * 4 + r;
      c_reg[r]    = c0[row * 1024 + col_h];
      mask_reg[r] = mask_h[row * 1024 + col_h];
    }
  }

  // mh store base (packed u64: block's 4 cols contiguous e).
  const int mh_lin_base = ((w * 32 + (bk >> 3)) * 64 + (((bk >> 1) & 3) * 16 + quad * 4)) * 8
                          + (bk & 1) * 4;   // + r*8 per r

  for (int s = 0; s < SEQ; ++s) {
    const u16* mi = mh_seq + (size_t)s * 65536;        // step-s input
    u16*       mo = mh_seq + (size_t)(s + 1) * 65536;  // step-s output

    // ---- 1. prefetch this wave's mh K-slice: 16 bypass loads, issued FIRST
    // so their MALL latency overlaps the x-projection below.
    union { u32x4 r; bf16x8 v; } hf[16];
    #pragma unroll
    for (int m = 0; m < 4; ++m)
      #pragma unroll
      for (int kw = 0; kw < 4; ++kw) {
        const u32 off = (u32)((m * 32 + w * 4 + kw) * 1024 + l * 16);
        asm volatile("global_load_dwordx4 %0, %1, %2 sc0 sc1"
                     : "=v"(hf[m * 4 + kw].r) : "v"(off), "s"(mi) : "memory");
      }

    // ---- 2. x-projection: no cross-step dependency.
    f32x4 acc[4];
    #pragma unroll
    for (int m = 0; m < 4; ++m) acc[m] = (f32x4){0.f, 0.f, 0.f, 0.f};
    #pragma unroll
    for (int kw = 0; kw < 4; ++kw) {
      bf16x8 a[4];
      #pragma unroll
      for (int m = 0; m < 4; ++m)
        a[m] = ApV[((s * 4 + m) * 32 + w * 4 + kw) * 64 + l];
      #pragma unroll
      for (int m = 0; m < 4; ++m)
        acc[m] = __builtin_amdgcn_mfma_f32_16x16x32_bf16(a[m], wi[kw], acc[m], 0, 0, 0);
    }

    // ---- 3. dataflow poll: re-load until no fragment contains the sentinel.
    // u64 producer stores are atomic => one u16 check per u64 suffices
    // (r[0] covers e0-3's u64, r[2] covers e4-7's u64).
    {
      int spins = 0;
      for (;;) {
        asm volatile("s_waitcnt vmcnt(0)" ::: "memory");
        __builtin_amdgcn_sched_barrier(0);   // rule #18: pin checks after wait
        int bad = 0;
        #pragma unroll
        for (int f = 0; f < 16; ++f) {
          bad |= (int)((hf[f].r[0] & 0xFFFFu) == 0xFFFFu);
          bad |= (int)((hf[f].r[2] & 0xFFFFu) == 0xFFFFu);
        }
        if (!__any(bad)) break;
        if (++spins > (1 << 13)) break;   // failsafe: never hang the queue
        #pragma unroll
        for (int m = 0; m < 4; ++m)
          #pragma unroll
          for (int kw = 0; kw < 4; ++kw) {
            const u32 off = (u32)((m * 32 + w * 4 + kw) * 1024 + l * 16);
            asm volatile("global_load_dwordx4 %0, %1, %2 sc0 sc1"
                         : "=v"(hf[m * 4 + kw].r) : "v"(off), "s"(mi) : "memory");
          }
      }
      __builtin_amdgcn_sched_barrier(0);   // pin MFMAs after the final check
    }

    // ---- 4. recurrent MFMAs.
    #pragma unroll
    for (int kw = 0; kw < 4; ++kw)
      #pragma unroll
      for (int m = 0; m < 4; ++m)
        acc[m] = __builtin_amdgcn_mfma_f32_16x16x32_bf16(hf[m * 4 + kw].v, wh[kw], acc[m], 0, 0, 0);

    #pragma unroll
    for (int m = 0; m < 4; ++m) lds[w][m][l] = acc[m];
    __syncthreads();   // #1: LDS writes -> reduce

    // ---- 5. epilogue (waves 0-3): reduce, cell, mh u64 stores fire-and-forget.
    if (w < 4) {
      f32x4 t = lds[0][w][l];
      #pragma unroll
      for (int ww = 1; ww < 8; ++ww) t += lds[ww][w][l];

      f32x4 ho_s[4];
      f32x4 co_s[4];
      #pragma unroll
      for (int r = 0; r < 4; ++r) {
        const float gp = t[r] + bias_reg;
        const float v1 = __shfl_xor(gp, 1, 64);
        const float v2 = __shfl_xor(gp, 2, 64);
        const float v3 = __shfl_xor(gp, 3, 64);
        const float ig = pick4(g_role,     gp, v1, v2, v3);
        const float fg = pick4(g_role ^ 1, gp, v1, v2, v3);
        const float gg = pick4(g_role ^ 2, gp, v1, v2, v3);
        const float og = pick4(g_role ^ 3, gp, v1, v2, v3);
        const float iv = sigm(ig);
        const float fv = sigm(fg);
        const float gv = tanh_fast(gg);
        const float ov = sigm(og);
        const float cn = fv * c_reg[r] + iv * gv;
        c_reg[r] = cn;
        const float hn = ov * tanh_fast(cn);
        const float mv = hn * mask_reg[r];

        // gather the block's 4 h-cols into the jh==0 lanes (g_role==0)
        const float h1 = __shfl_xor(hn, 4, 64);
        const float h2 = __shfl_xor(hn, 8, 64);
        const float h3 = __shfl_xor(hn, 12, 64);
        const float m1 = __shfl_xor(mv, 4, 64);
        const float m2 = __shfl_xor(mv, 8, 64);
        const float m3 = __shfl_xor(mv, 12, 64);
        ho_s[r] = (f32x4){hn, h1, h2, h3};
        if (s == SEQ - 1) {
          const float cn1 = __shfl_xor(cn, 4, 64);
          const float cn2 = __shfl_xor(cn, 8, 64);
          const float cn3 = __shfl_xor(cn, 12, 64);
          co_s[r] = (f32x4){cn, cn1, cn2, cn3};
        }
        if (nl == 0) {
          // The store IS the signal: atomic u64, write-through to the MALL.
          const u64 pk = (u64)f2bf(mv) | ((u64)f2bf(m1) << 16)
                       | ((u64)f2bf(m2) << 32) | ((u64)f2bf(m3) << 48);
          __hip_atomic_store((u64*)&mo[mh_lin_base + r * 8], pk,
                             __ATOMIC_RELAXED, __HIP_MEMORY_SCOPE_AGENT);
        }
      }
      // out stores (never on the inter-block critical path)
      if (nl == 0) {
        #pragma unroll
        for (int r = 0; r < 4; ++r) {
          const int row = w * 16 + quad * 4 + r;
          *(f32x4*)&out[((size_t)s * 64 + row) * 1024 + bk * 4] = ho_s[r];
          if (s == SEQ - 1) {
            *(f32x4*)&out[16777216 + row * 1024 + bk * 4] = ho_s[r];        // h_n
            *(f32x4*)&out[16777216 + 65536 + row * 1024 + bk * 4] = co_s[r];// c_n
          }
        }
      }
    }
    __syncthreads();   // #2: WAR protection for lds + step advance
  }
}

// ---------------------------------------------------------------------------
// Fallback per-step kernel (R3, unchanged): used only when ws is too small.
// ---------------------------------------------------------------------------
__global__ __launch_bounds__(256) void lstm_step(
    const u16* __restrict__ Ap,
    const u16* __restrict__ Wihp,
    const u16* __restrict__ Whhp,
    const _Float16* __restrict__ xg,  // null => fold x-GEMM
    const float* __restrict__ bias,
    const u16* __restrict__ mh_in, u16* __restrict__ mh_out,
    float* __restrict__ c, const float* __restrict__ mask_h,
    float* __restrict__ out, int s)
{
  __shared__ f32x4 lds[4][4][64];   // [w][m][l] 16 KB

  const int tid = threadIdx.x;
  const int w   = tid >> 6;      // K-slice
  const int l   = tid & 63;
  const int bk  = blockIdx.x;    // 4 h-cols

  const bf16x8* mb = (const bf16x8*)mh_in;
  const bf16x8* WH = (const bf16x8*)Whhp;

  f32x4 acc[4] = { {0,0,0,0}, {0,0,0,0}, {0,0,0,0}, {0,0,0,0} };

  #pragma unroll 2
  for (int kw = 0; kw < 8; ++kw) {
    bf16x8 b = WH[(bk * 32 + w * 8 + kw) * 64 + l];
    #pragma unroll
    for (int m = 0; m < 4; ++m) {
      bf16x8 a = mb[(m * 32 + w * 8 + kw) * 64 + l];
      acc[m] = __builtin_amdgcn_mfma_f32_16x16x32_bf16(a, b, acc[m], 0, 0, 0);
    }
  }
  if (xg == nullptr) {   // fold x-projection
    const bf16x8* ApV = (const bf16x8*)Ap;
    const bf16x8* WI  = (const bf16x8*)Wihp;
    #pragma unroll 2
    for (int kw = 0; kw < 8; ++kw) {
      bf16x8 b = WI[(bk * 32 + w * 8 + kw) * 64 + l];
      #pragma unroll
      for (int m = 0; m < 4; ++m) {
        bf16x8 a = ApV[((s * 4 + m) * 32 + w * 8 + kw) * 64 + l];
        acc[m] = __builtin_amdgcn_mfma_f32_16x16x32_bf16(a, b, acc[m], 0, 0, 0);
      }
    }
  }
  #pragma unroll
  for (int m = 0; m < 4; ++m) lds[w][m][l] = acc[m];
  __syncthreads();

  f32x4 t = lds[0][w][l];
  #pragma unroll
  for (int ww = 1; ww < 4; ++ww) t += lds[ww][w][l];

  const int nl     = l & 15;
  const int quad   = l >> 4;
  const int g_role = nl & 3;
  const int jh     = nl >> 2;
  const int col_h  = bk * 4 + jh;

  if (xg != nullptr) {
    f16x4 xv = *(const f16x4*)&xg[((((size_t)s * 256 + bk) * 4 + w) * 64 + l) * 4];
    #pragma unroll
    for (int r = 0; r < 4; ++r) t[r] += (float)xv[r];
  }
  const float bias_reg = bias[g_role * 1024 + col_h];
  const int kwg = col_h >> 5;
  const int lp  = ((col_h >> 3) & 3) * 16;

  #pragma unroll
  for (int r = 0; r < 4; ++r) {
    const int b_row = w * 16 + quad * 4 + r;
    const float gp = t[r] + bias_reg;
    const float v1 = __shfl_xor(gp, 1, 64);
    const float v2 = __shfl_xor(gp, 2, 64);
    const float v3 = __shfl_xor(gp, 3, 64);
    const float ig = pick4(g_role,     gp, v1, v2, v3);
    const float fg = pick4(g_role ^ 1, gp, v1, v2, v3);
    const float gg = pick4(g_role ^ 2, gp, v1, v2, v3);
    const float og = pick4(g_role ^ 3, gp, v1, v2, v3);
    const float iv = sigm(ig);
    const float fv = sigm(fg);
    const float gv = tanh_fast(gg);
    const float ov = sigm(og);
    const float cold = c[b_row * 1024 + col_h];
    const float cn = fv * cold + iv * gv;
    const float hn = ov * tanh_fast(cn);
    if (g_role == 0) {
      c[b_row * 1024 + col_h] = cn;
      out[((size_t)s * 64 + b_row) * 1024 + col_h] = hn;
      mh_out[((w * 32 + kwg) * 64 + (lp + (b_row & 15))) * 8 + (col_h & 7)] =
          f2bf(hn * mask_h[b_row * 1024 + col_h]);
      if (s == SEQ - 1) {
        out[16777216 + b_row * 1024 + col_h] = hn;           // h_n
        out[16777216 + 65536 + b_row * 1024 + col_h] = cn;   // c_n
      }
    }
  }
}

extern "C" void kernel_launch(void* const* d_in, const int* in_sizes, int n_in,
                              void* d_out, int out_size, void* d_ws, size_t ws_size,
                              hipStream_t stream)
{
  const float* x      = (const float*)d_in[0];
  const float* h0     = (const float*)d_in[1];
  const float* c0     = (const float*)d_in[2];
  const float* mask_x = (const float*)d_in[3];
  const float* mask_h = (const float*)d_in[4];
  const float* Wih    = (const float*)d_in[5];
  const float* Whh    = (const float*)d_in[6];
  const float* bih    = (const float*)d_in[7];
  const float* bhh    = (const float*)d_in[8];
  float* out = (float*)d_out;

  char* ws = (char*)d_ws;
  u16*   Wihp   = (u16*)(ws + 0);
  u16*   Whhp   = (u16*)(ws + 8388608);
  u16*   Ap     = (u16*)(ws + 16777216);
  u16*   mh0    = (u16*)(ws + 50331648);
  u16*   mh1    = (u16*)(ws + 50462720);
  float* bias   = (float*)(ws + 50593792);
  float* c      = (float*)(ws + 50610176);
  u16*   mh_seq = (u16*)(ws + 50873344);   // 257 x 131072 B, end 84558848
  const bool persist = (ws_size >= (size_t)84558848);

  u16* mh_init = persist ? mh_seq : mh0;   // prep writes the step-0 mh here

  hipLaunchKernelGGL(prep_kernel, dim3(8192), dim3(256), 0, stream,
                     x, h0, c0, mask_x, mask_h, Wih, Whh, bih, bhh,
                     Wihp, Whhp, Ap, mh_init, bias, c, mh_seq, (int)persist);

  if (persist) {
    hipLaunchKernelGGL(lstm_persist, dim3(256), dim3(512), 0, stream,
                       Ap, Wihp, Whhp, bias, c0, mask_h, mh_seq, out);
  } else {
    for (int s = 0; s < SEQ; ++s) {
      const u16* mi = (s & 1) ? mh1 : mh0;
      u16*       mo = (s & 1) ? mh0 : mh1;
      hipLaunchKernelGGL(lstm_step, dim3(256), dim3(256), 0, stream,
                         Ap, Wihp, Whhp, (const _Float16*)nullptr, bias, mi, mo,
                         c, mask_h, out, s);
    }
  }
}

// Round 7
// 1011.322 us; speedup vs baseline: 1.7029x; 1.7029x over previous
//
#include <hip/hip_runtime.h>
#include <stdint.h>
#include <stddef.h>

// Variational-dropout LSTM, SEQ=256, B=64, IN=H=1024, fp32 I/O.
//
// R10: 2-D output tiling on R6's proven protocol. 256 blocks = 4 row-groups
// (rg) x 64 col-groups (cg). Block (rg,cg) computes gates[16 rows x 64
// gate-cols]: same compute as R6 (16+16 MFMAs/wave/step), but reads only
// mh[16 rows] = 32 KB (1/4 of R6) and 1/4 the Ap slice -> mh MALL reads
// 32 -> 8 MB/step, 4 bypass loads/wave instead of 16. Handshake = R6:
// wave-0 flag poll (dwordx4 sc0 sc1), bypass mh loads after the gate,
// write-through u64 mh stores, vmcnt(0) drain -> LDS counter -> last
// arriver releases the flag BEFORE out stores. All 8 waves split the
// epilogue (wave w: n-tile w&3, row-pair (w>>2)*2). Lessons kept: no
// fences (R5), no cached mh (R7), no sentinel data-poll (R9), don't cut
// block count (R8). Prep: vectorized (R9), no sentinel fill.
// Fallback (small ws): R3's per-step launch path, unchanged.

#define SEQ 256

typedef __attribute__((ext_vector_type(8))) __bf16 bf16x8;
typedef __attribute__((ext_vector_type(4))) float  f32x4;
typedef __attribute__((ext_vector_type(4))) _Float16 f16x4;
typedef __attribute__((ext_vector_type(4))) unsigned int u32x4;
typedef unsigned short u16;
typedef unsigned int   u32;
typedef unsigned long long u64;

__device__ __forceinline__ u16 f2bf(float f) {
  union { float f; unsigned u; } v; v.f = f;
  unsigned r = v.u + 0x7FFFu + ((v.u >> 16) & 1u);   // RNE
  return (u16)(r >> 16);
}
__device__ __forceinline__ float sigm(float x) {
  return __builtin_amdgcn_rcpf(1.f + __expf(-x));
}
__device__ __forceinline__ float tanh_fast(float x) {
  float xc = fminf(15.f, fmaxf(-15.f, x));
  float t = __expf(-2.f * xc);
  return (1.f - t) * __builtin_amdgcn_rcpf(1.f + t);
}
__device__ __forceinline__ float pick4(int idx, float v0, float v1, float v2, float v3) {
  float lo = (idx & 1) ? v1 : v0;
  float hi = (idx & 1) ? v3 : v2;
  return (idx & 2) ? hi : lo;
}

// ws layout (bytes):
//  Wihp  @ 0         : [wb 256][kcw 32][l 64][e 8] bf16 = 8388608
//  Whhp  @ 8388608   : same = 8388608
//  Ap    @ 16777216  : [s 256][m 4][kwg 32][l 64][e 8] bf16 = 33554432
//  mh0   @ 50331648  : [m 4][kwg 32][l 64][e 8] bf16 = 131072   (fallback)
//  mh1   @ 50462720  : 131072                                   (fallback)
//  bias  @ 50593792  : 4096 f32 = 16384
//  c     @ 50610176  : [b 64][col 1024] f32 = 262144            (fallback)
//  flags @ 50872320  : 256 u32 = 1024       (base end: 50873344)
//  mh_seq@ 50873344  : 257 x 131072 = 33685504   (end: 84558848)

// Vectorized prep: grid 8192 x 256, each thread handles 8 contiguous u16.
__global__ __launch_bounds__(256) void prep_kernel(
    const float* __restrict__ x, const float* __restrict__ h0,
    const float* __restrict__ c0, const float* __restrict__ mask_x,
    const float* __restrict__ mask_h, const float* __restrict__ Wih,
    const float* __restrict__ Whh, const float* __restrict__ bih,
    const float* __restrict__ bhh,
    u16* __restrict__ Wihp, u16* __restrict__ Whhp, u16* __restrict__ Ap,
    u16* __restrict__ mhp0, float* __restrict__ bias, float* __restrict__ c,
    u32* __restrict__ flags, int persist)
{
  const unsigned t    = blockIdx.x * 256u + threadIdx.x;  // 0 .. 2097151
  const unsigned idx8 = t * 8u;

  union Pack8 { u16 o[8]; u32x4 v; };

  // Ap[s][m][kwg][l][e0..7] = bf16( x * mask_x ), 8 contiguous k per thread
  {
    const unsigned l   = (idx8 >> 3) & 63u;
    const unsigned kwg = (idx8 >> 9) & 31u;
    const unsigned m   = (idx8 >> 14) & 3u;
    const unsigned s   = idx8 >> 16;
    const unsigned b   = m * 16u + (l & 15u);
    const unsigned k   = kwg * 32u + (l >> 4) * 8u;
    const float* xp = &x[((size_t)s * 64u + b) * 1024u + k];
    const float* mp = &mask_x[b * 1024u + k];
    Pack8 p;
    #pragma unroll
    for (int e = 0; e < 8; ++e) p.o[e] = f2bf(xp[e] * mp[e]);
    *(u32x4*)&Ap[idx8] = p.v;
  }
  // W swizzles: n = (nl&3)*1024 + wb*4 + (nl>>2), 8 contiguous k
  if (t < 524288u) {
    const unsigned l   = (idx8 >> 3) & 63u;
    const unsigned kcw = (idx8 >> 9) & 31u;
    const unsigned wb  = idx8 >> 14;
    const unsigned nl  = l & 15u;
    const unsigned n   = (nl & 3u) * 1024u + wb * 4u + (nl >> 2);
    const unsigned k   = kcw * 32u + (l >> 4) * 8u;
    const float* wip = &Wih[n * 1024u + k];
    const float* whp = &Whh[n * 1024u + k];
    Pack8 pi, ph;
    #pragma unroll
    for (int e = 0; e < 8; ++e) { pi.o[e] = f2bf(wip[e]); ph.o[e] = f2bf(whp[e]); }
    *(u32x4*)&Wihp[idx8] = pi.v;
    *(u32x4*)&Whhp[idx8] = ph.v;
  }
  // mh slot 0 = bf16(h0 * mask_h); c init (fallback path)
  if (t < 8192u) {
    const unsigned l   = (idx8 >> 3) & 63u;
    const unsigned kwg = (idx8 >> 9) & 31u;
    const unsigned m   = idx8 >> 14;
    const unsigned b   = m * 16u + (l & 15u);
    const unsigned k   = kwg * 32u + (l >> 4) * 8u;
    const float* hp = &h0[b * 1024u + k];
    const float* mp = &mask_h[b * 1024u + k];
    Pack8 p;
    #pragma unroll
    for (int e = 0; e < 8; ++e) p.o[e] = f2bf(hp[e] * mp[e]);
    *(u32x4*)&mhp0[idx8] = p.v;
    *(f32x4*)&c[idx8]     = *(const f32x4*)&c0[idx8];
    *(f32x4*)&c[idx8 + 4] = *(const f32x4*)&c0[idx8 + 4];
  }
  if (t < 512u) {
    #pragma unroll
    for (int e = 0; e < 8; ++e) bias[idx8 + e] = bih[idx8 + e] + bhh[idx8 + e];
  }
  if (persist && t < 256u) flags[t] = 0u;
}

// ---------------------------------------------------------------------------
// Persistent recurrence kernel: 256 blocks x 512 threads, all 256 steps.
// Block (rg = bk>>6, cg = bk&63) owns rows [rg*16, rg*16+16) x h-cols
// [cg*16, cg*16+16) (x4 gates). Wave w owns K-slice [w*128, (w+1)*128).
// ---------------------------------------------------------------------------
__global__ __launch_bounds__(512) void lstm_persist(
    const u16* __restrict__ Ap, const u16* __restrict__ Wihp,
    const u16* __restrict__ Whhp, const float* __restrict__ bias,
    const float* __restrict__ c0, const float* __restrict__ mask_h,
    u16* __restrict__ mh_seq,
    u32* __restrict__ flags, float* __restrict__ out)
{
  __shared__ f32x4 lds[8][4][64];   // [ww][nt][l] 32 KB
  __shared__ u32 cnt;               // epilogue arrive counter

  const int tid = threadIdx.x;
  const int w   = tid >> 6;       // K-slice 0..7
  const int l   = tid & 63;
  const int bk  = blockIdx.x;
  const int rg  = bk >> 6;        // row-group 0..3 (16 batch rows)
  const int cg  = bk & 63;        // col-group 0..63 (16 h-cols)

  const bf16x8* WHV = (const bf16x8*)Whhp;
  const bf16x8* WIV = (const bf16x8*)Wihp;
  const bf16x8* ApV = (const bf16x8*)Ap;

  // Weights resident in registers for the whole sequence: 4 n-tiles x 4 kw.
  bf16x8 wh[4][4], wi[4][4];
  #pragma unroll
  for (int nt = 0; nt < 4; ++nt)
    #pragma unroll
    for (int kw = 0; kw < 4; ++kw) {
      wh[nt][kw] = WHV[((cg * 4 + nt) * 32 + w * 4 + kw) * 64 + l];
      wi[nt][kw] = WIV[((cg * 4 + nt) * 32 + w * 4 + kw) * 64 + l];
    }

  const int nl     = l & 15;
  const int quad   = l >> 4;
  const int g_role = nl & 3;
  const int jh     = nl >> 2;

  // Epilogue assignment: wave w handles n-tile (w&3), rows r in {rb, rb+1}.
  const int nt_e  = w & 3;
  const int rb    = (w >> 2) * 2;
  const int col_h = cg * 16 + nt_e * 4 + jh;
  const float bias_reg = bias[g_role * 1024 + col_h];
  float c_reg[2], mask_reg[2];
  #pragma unroll
  for (int rl = 0; rl < 2; ++rl) {
    const int row = rg * 16 + quad * 4 + rb + rl;
    c_reg[rl]    = c0[row * 1024 + col_h];
    mask_reg[rl] = mask_h[row * 1024 + col_h];
  }

  // mh store base (u16 units) for nl==0 lanes: fragment (m=rg, kwg=cg>>1),
  // l_t = ((cg&1)*2 + (nt_e>>1))*16 + row16, e = (nt_e&1)*4 + jh.
  const int mh_u16_base =
      ((rg * 32 + (cg >> 1)) * 64 + ((cg & 1) * 2 + (nt_e >> 1)) * 16 + quad * 4) * 8
      + (nt_e & 1) * 4;   // + (rb+rl)*8 per row

  if (tid == 0) cnt = 0u;
  __syncthreads();

  for (int s = 0; s < SEQ; ++s) {
    const u16* mi = mh_seq + (size_t)s * 65536;        // step-s input
    u16*       mo = mh_seq + (size_t)(s + 1) * 65536;  // step-s output

    // ---- 1. x-projection (no cross-step dependency; overlaps stragglers).
    f32x4 acc[4];
    #pragma unroll
    for (int nt = 0; nt < 4; ++nt) acc[nt] = (f32x4){0.f, 0.f, 0.f, 0.f};
    #pragma unroll
    for (int kw = 0; kw < 4; ++kw) {
      bf16x8 a = ApV[((s * 4 + rg) * 32 + w * 4 + kw) * 64 + l];
      #pragma unroll
      for (int nt = 0; nt < 4; ++nt)
        acc[nt] = __builtin_amdgcn_mfma_f32_16x16x32_bf16(a, wi[nt][kw], acc[nt], 0, 0, 0);
    }

    // ---- 2. gate: wave 0 polls all 256 flags (4 per lane, one dwordx4).
    if (s > 0) {
      if (w == 0) {
        const u32 target = (u32)s;
        const u32 poff = (u32)(l * 16);
        int spins = 0;
        for (;;) {
          u32x4 f;
          asm volatile("global_load_dwordx4 %0, %1, %2 sc0 sc1\n\t"
                       "s_waitcnt vmcnt(0)"
                       : "=v"(f) : "v"(poff), "s"(flags) : "memory");
          bool ok = (f[0] >= target) & (f[1] >= target) &
                    (f[2] >= target) & (f[3] >= target);
          if (__all(ok)) break;
          if (++spins > (1 << 15)) break;   // failsafe: never hang the queue
          __builtin_amdgcn_s_sleep(1);
        }
      }
      __syncthreads();
    }

    // ---- 3. recurrent part: only 4 bypass fragments (rows rg*16..+16).
    union { u32x4 r; bf16x8 v; } hf[4];
    #pragma unroll
    for (int kw = 0; kw < 4; ++kw) {
      const u32 off = (u32)(((rg * 32 + w * 4 + kw) * 64 + l) * 16);
      asm volatile("global_load_dwordx4 %0, %1, %2 sc0 sc1"
                   : "=v"(hf[kw].r) : "v"(off), "s"(mi) : "memory");
    }
    asm volatile("s_waitcnt vmcnt(0)" ::: "memory");
    __builtin_amdgcn_sched_barrier(0);   // rule #18: pin MFMAs after the wait
    #pragma unroll
    for (int kw = 0; kw < 4; ++kw)
      #pragma unroll
      for (int nt = 0; nt < 4; ++nt)
        acc[nt] = __builtin_amdgcn_mfma_f32_16x16x32_bf16(hf[kw].v, wh[nt][kw], acc[nt], 0, 0, 0);

    #pragma unroll
    for (int nt = 0; nt < 4; ++nt) lds[w][nt][l] = acc[nt];
    __syncthreads();   // #1: LDS writes -> reduce

    // ---- 4. epilogue: all 8 waves; wave w reduces n-tile nt_e, rows rb,rb+1.
    f32x4 t = lds[0][nt_e][l];
    #pragma unroll
    for (int ww = 1; ww < 8; ++ww) t += lds[ww][nt_e][l];

    f32x4 ho_s[2];
    f32x4 co_s[2];
    #pragma unroll
    for (int rl = 0; rl < 2; ++rl) {
      const int r = rb + rl;
      const float gp = t[r] + bias_reg;
      const float v1 = __shfl_xor(gp, 1, 64);
      const float v2 = __shfl_xor(gp, 2, 64);
      const float v3 = __shfl_xor(gp, 3, 64);
      const float ig = pick4(g_role,     gp, v1, v2, v3);
      const float fg = pick4(g_role ^ 1, gp, v1, v2, v3);
      const float gg = pick4(g_role ^ 2, gp, v1, v2, v3);
      const float og = pick4(g_role ^ 3, gp, v1, v2, v3);
      const float iv = sigm(ig);
      const float fv = sigm(fg);
      const float gv = tanh_fast(gg);
      const float ov = sigm(og);
      const float cn = fv * c_reg[rl] + iv * gv;
      c_reg[rl] = cn;
      const float hn = ov * tanh_fast(cn);
      const float mv = hn * mask_reg[rl];

      // gather the n-tile's 4 h-cols (jh) into the nl==0 lanes
      const float h1 = __shfl_xor(hn, 4, 64);
      const float h2 = __shfl_xor(hn, 8, 64);
      const float h3 = __shfl_xor(hn, 12, 64);
      const float m1 = __shfl_xor(mv, 4, 64);
      const float m2 = __shfl_xor(mv, 8, 64);
      const float m3 = __shfl_xor(mv, 12, 64);
      ho_s[rl] = (f32x4){hn, h1, h2, h3};
      if (s == SEQ - 1) {
        const float cn1 = __shfl_xor(cn, 4, 64);
        const float cn2 = __shfl_xor(cn, 8, 64);
        const float cn3 = __shfl_xor(cn, 12, 64);
        co_s[rl] = (f32x4){cn, cn1, cn2, cn3};
      }
      if (nl == 0) {
        // mh store FIRST (the only store other blocks wait on) — agent
        // scope write-through so it reaches the MALL before the flag.
        const u64 pk = (u64)f2bf(mv) | ((u64)f2bf(m1) << 16)
                     | ((u64)f2bf(m2) << 32) | ((u64)f2bf(m3) << 48);
        __hip_atomic_store((u64*)&mo[mh_u16_base + r * 8], pk,
                           __ATOMIC_RELAXED, __HIP_MEMORY_SCOPE_AGENT);
      }
    }
    // drain mh stores, arrive; LAST wave releases the flag. Out stores after.
    asm volatile("s_waitcnt vmcnt(0)" ::: "memory");
    u32 old = 0u;
    if (l == 0)
      old = __hip_atomic_fetch_add(&cnt, 1u, __ATOMIC_RELAXED, __HIP_MEMORY_SCOPE_WORKGROUP);
    if (l == 0 && old == 7u) {
      __hip_atomic_store(&cnt, 0u, __ATOMIC_RELAXED, __HIP_MEMORY_SCOPE_WORKGROUP);
      if (s < SEQ - 1) {
        u32 val  = (u32)(s + 1);
        u32 voff = (u32)(bk * 4);
        asm volatile("global_store_dword %0, %1, %2 sc0 sc1"
                     :: "v"(voff), "v"(val), "s"(flags) : "memory");
      }
    }
    if (nl == 0) {
      #pragma unroll
      for (int rl = 0; rl < 2; ++rl) {
        const int row = rg * 16 + quad * 4 + rb + rl;
        *(f32x4*)&out[((size_t)s * 64 + row) * 1024 + cg * 16 + nt_e * 4] = ho_s[rl];
        if (s == SEQ - 1) {
          *(f32x4*)&out[16777216 + row * 1024 + cg * 16 + nt_e * 4] = ho_s[rl];         // h_n
          *(f32x4*)&out[16777216 + 65536 + row * 1024 + cg * 16 + nt_e * 4] = co_s[rl]; // c_n
        }
      }
    }
    __syncthreads();   // #2: WAR protection for lds + cnt + step advance
  }
}

// ---------------------------------------------------------------------------
// Fallback per-step kernel (R3, unchanged): used only when ws is too small.
// ---------------------------------------------------------------------------
__global__ __launch_bounds__(256) void lstm_step(
    const u16* __restrict__ Ap,
    const u16* __restrict__ Wihp,
    const u16* __restrict__ Whhp,
    const _Float16* __restrict__ xg,  // null => fold x-GEMM
    const float* __restrict__ bias,
    const u16* __restrict__ mh_in, u16* __restrict__ mh_out,
    float* __restrict__ c, const float* __restrict__ mask_h,
    float* __restrict__ out, int s)
{
  __shared__ f32x4 lds[4][4][64];   // [w][m][l] 16 KB

  const int tid = threadIdx.x;
  const int w   = tid >> 6;      // K-slice
  const int l   = tid & 63;
  const int bk  = blockIdx.x;    // 4 h-cols

  const bf16x8* mb = (const bf16x8*)mh_in;
  const bf16x8* WH = (const bf16x8*)Whhp;

  f32x4 acc[4] = { {0,0,0,0}, {0,0,0,0}, {0,0,0,0}, {0,0,0,0} };

  #pragma unroll 2
  for (int kw = 0; kw < 8; ++kw) {
    bf16x8 b = WH[(bk * 32 + w * 8 + kw) * 64 + l];
    #pragma unroll
    for (int m = 0; m < 4; ++m) {
      bf16x8 a = mb[(m * 32 + w * 8 + kw) * 64 + l];
      acc[m] = __builtin_amdgcn_mfma_f32_16x16x32_bf16(a, b, acc[m], 0, 0, 0);
    }
  }
  if (xg == nullptr) {   // fold x-projection
    const bf16x8* ApV = (const bf16x8*)Ap;
    const bf16x8* WI  = (const bf16x8*)Wihp;
    #pragma unroll 2
    for (int kw = 0; kw < 8; ++kw) {
      bf16x8 b = WI[(bk * 32 + w * 8 + kw) * 64 + l];
      #pragma unroll
      for (int m = 0; m < 4; ++m) {
        bf16x8 a = ApV[((s * 4 + m) * 32 + w * 8 + kw) * 64 + l];
        acc[m] = __builtin_amdgcn_mfma_f32_16x16x32_bf16(a, b, acc[m], 0, 0, 0);
      }
    }
  }
  #pragma unroll
  for (int m = 0; m < 4; ++m) lds[w][m][l] = acc[m];
  __syncthreads();

  f32x4 t = lds[0][w][l];
  #pragma unroll
  for (int ww = 1; ww < 4; ++ww) t += lds[ww][w][l];

  const int nl     = l & 15;
  const int quad   = l >> 4;
  const int g_role = nl & 3;
  const int jh     = nl >> 2;
  const int col_h  = bk * 4 + jh;

  if (xg != nullptr) {
    f16x4 xv = *(const f16x4*)&xg[((((size_t)s * 256 + bk) * 4 + w) * 64 + l) * 4];
    #pragma unroll
    for (int r = 0; r < 4; ++r) t[r] += (float)xv[r];
  }
  const float bias_reg = bias[g_role * 1024 + col_h];
  const int kwg = col_h >> 5;
  const int lp  = ((col_h >> 3) & 3) * 16;

  #pragma unroll
  for (int r = 0; r < 4; ++r) {
    const int b_row = w * 16 + quad * 4 + r;
    const float gp = t[r] + bias_reg;
    const float v1 = __shfl_xor(gp, 1, 64);
    const float v2 = __shfl_xor(gp, 2, 64);
    const float v3 = __shfl_xor(gp, 3, 64);
    const float ig = pick4(g_role,     gp, v1, v2, v3);
    const float fg = pick4(g_role ^ 1, gp, v1, v2, v3);
    const float gg = pick4(g_role ^ 2, gp, v1, v2, v3);
    const float og = pick4(g_role ^ 3, gp, v1, v2, v3);
    const float iv = sigm(ig);
    const float fv = sigm(fg);
    const float gv = tanh_fast(gg);
    const float ov = sigm(og);
    const float cold = c[b_row * 1024 + col_h];
    const float cn = fv * cold + iv * gv;
    const float hn = ov * tanh_fast(cn);
    if (g_role == 0) {
      c[b_row * 1024 + col_h] = cn;
      out[((size_t)s * 64 + b_row) * 1024 + col_h] = hn;
      mh_out[((w * 32 + kwg) * 64 + (lp + (b_row & 15))) * 8 + (col_h & 7)] =
          f2bf(hn * mask_h[b_row * 1024 + col_h]);
      if (s == SEQ - 1) {
        out[16777216 + b_row * 1024 + col_h] = hn;           // h_n
        out[16777216 + 65536 + b_row * 1024 + col_h] = cn;   // c_n
      }
    }
  }
}

extern "C" void kernel_launch(void* const* d_in, const int* in_sizes, int n_in,
                              void* d_out, int out_size, void* d_ws, size_t ws_size,
                              hipStream_t stream)
{
  const float* x      = (const float*)d_in[0];
  const float* h0     = (const float*)d_in[1];
  const float* c0     = (const float*)d_in[2];
  const float* mask_x = (const float*)d_in[3];
  const float* mask_h = (const float*)d_in[4];
  const float* Wih    = (const float*)d_in[5];
  const float* Whh    = (const float*)d_in[6];
  const float* bih    = (const float*)d_in[7];
  const float* bhh    = (const float*)d_in[8];
  float* out = (float*)d_out;

  char* ws = (char*)d_ws;
  u16*   Wihp   = (u16*)(ws + 0);
  u16*   Whhp   = (u16*)(ws + 8388608);
  u16*   Ap     = (u16*)(ws + 16777216);
  u16*   mh0    = (u16*)(ws + 50331648);
  u16*   mh1    = (u16*)(ws + 50462720);
  float* bias   = (float*)(ws + 50593792);
  float* c      = (float*)(ws + 50610176);
  u32*   flags  = (u32*)(ws + 50872320);
  u16*   mh_seq = (u16*)(ws + 50873344);   // 257 x 131072 B, end 84558848
  const bool persist = (ws_size >= (size_t)84558848);

  u16* mh_init = persist ? mh_seq : mh0;   // prep writes the step-0 mh here

  hipLaunchKernelGGL(prep_kernel, dim3(8192), dim3(256), 0, stream,
                     x, h0, c0, mask_x, mask_h, Wih, Whh, bih, bhh,
                     Wihp, Whhp, Ap, mh_init, bias, c, flags, (int)persist);

  if (persist) {
    hipLaunchKernelGGL(lstm_persist, dim3(256), dim3(512), 0, stream,
                       Ap, Wihp, Whhp, bias, c0, mask_h, mh_seq, flags, out);
  } else {
    for (int s = 0; s < SEQ; ++s) {
      const u16* mi = (s & 1) ? mh1 : mh0;
      u16*       mo = (s & 1) ? mh0 : mh1;
      hipLaunchKernelGGL(lstm_step, dim3(256), dim3(256), 0, stream,
                         Ap, Wihp, Whhp, (const _Float16*)nullptr, bias, mi, mo,
                         c, mask_h, out, s);
    }
  }
}

// Round 9
// 956.361 us; speedup vs baseline: 1.8007x; 1.0575x over previous
//
#include <hip/hip_runtime.h>
#include <stdint.h>
#include <stddef.h>

// Variational-dropout LSTM, SEQ=256, B=64, IN=H=1024, fp32 I/O.
//
// R11 (resubmit; previous round was a container-infra failure, not a kernel
// result): wave-granular flag dataflow on R10's 2-D tiling. Consumer wave w
// of block (rg,cg) reads mh fragments kwg=4w..4w+3 == h-cols [128w,128w+128),
// produced by exactly 8 blocks (rg, 8w..8w+7). So each wave polls ONLY its
// own 8 flags (1 dword/lane, dup mod 8 -> one 32B transaction) and proceeds
// independently -- the block-wide gate barrier is gone. Ready waves' mh
// loads overlap other waves' waiting; barrier #1 (LDS reduce) closes sooner.
// Producer side unchanged (R6-proven): write-through u64 mh stores ->
// vmcnt(0) -> LDS counter -> last arriver releases the flag BEFORE out
// stores. Lessons kept: no fences (R5), no cached mh (R7), don't cut block
// count (R8), no data-sentinel polling (R9).
// Fallback (small ws): R3's per-step launch path, unchanged.

#define SEQ 256

typedef __attribute__((ext_vector_type(8))) __bf16 bf16x8;
typedef __attribute__((ext_vector_type(4))) float  f32x4;
typedef __attribute__((ext_vector_type(4))) _Float16 f16x4;
typedef __attribute__((ext_vector_type(4))) unsigned int u32x4;
typedef unsigned short u16;
typedef unsigned int   u32;
typedef unsigned long long u64;

__device__ __forceinline__ u16 f2bf(float f) {
  union { float f; unsigned u; } v; v.f = f;
  unsigned r = v.u + 0x7FFFu + ((v.u >> 16) & 1u);   // RNE
  return (u16)(r >> 16);
}
__device__ __forceinline__ float sigm(float x) {
  return __builtin_amdgcn_rcpf(1.f + __expf(-x));
}
__device__ __forceinline__ float tanh_fast(float x) {
  float xc = fminf(15.f, fmaxf(-15.f, x));
  float t = __expf(-2.f * xc);
  return (1.f - t) * __builtin_amdgcn_rcpf(1.f + t);
}
__device__ __forceinline__ float pick4(int idx, float v0, float v1, float v2, float v3) {
  float lo = (idx & 1) ? v1 : v0;
  float hi = (idx & 1) ? v3 : v2;
  return (idx & 2) ? hi : lo;
}

// ws layout (bytes):
//  Wihp  @ 0         : [wb 256][kcw 32][l 64][e 8] bf16 = 8388608
//  Whhp  @ 8388608   : same = 8388608
//  Ap    @ 16777216  : [s 256][m 4][kwg 32][l 64][e 8] bf16 = 33554432
//  mh0   @ 50331648  : [m 4][kwg 32][l 64][e 8] bf16 = 131072   (fallback)
//  mh1   @ 50462720  : 131072                                   (fallback)
//  bias  @ 50593792  : 4096 f32 = 16384
//  c     @ 50610176  : [b 64][col 1024] f32 = 262144            (fallback)
//  flags @ 50872320  : 256 u32 = 1024       (base end: 50873344)
//  mh_seq@ 50873344  : 257 x 131072 = 33685504   (end: 84558848)

// Vectorized prep: grid 8192 x 256, each thread handles 8 contiguous u16.
__global__ __launch_bounds__(256) void prep_kernel(
    const float* __restrict__ x, const float* __restrict__ h0,
    const float* __restrict__ c0, const float* __restrict__ mask_x,
    const float* __restrict__ mask_h, const float* __restrict__ Wih,
    const float* __restrict__ Whh, const float* __restrict__ bih,
    const float* __restrict__ bhh,
    u16* __restrict__ Wihp, u16* __restrict__ Whhp, u16* __restrict__ Ap,
    u16* __restrict__ mhp0, float* __restrict__ bias, float* __restrict__ c,
    u32* __restrict__ flags, int persist)
{
  const unsigned t    = blockIdx.x * 256u + threadIdx.x;  // 0 .. 2097151
  const unsigned idx8 = t * 8u;

  union Pack8 { u16 o[8]; u32x4 v; };

  // Ap[s][m][kwg][l][e0..7] = bf16( x * mask_x ), 8 contiguous k per thread
  {
    const unsigned l   = (idx8 >> 3) & 63u;
    const unsigned kwg = (idx8 >> 9) & 31u;
    const unsigned m   = (idx8 >> 14) & 3u;
    const unsigned s   = idx8 >> 16;
    const unsigned b   = m * 16u + (l & 15u);
    const unsigned k   = kwg * 32u + (l >> 4) * 8u;
    const float* xp = &x[((size_t)s * 64u + b) * 1024u + k];
    const float* mp = &mask_x[b * 1024u + k];
    Pack8 p;
    #pragma unroll
    for (int e = 0; e < 8; ++e) p.o[e] = f2bf(xp[e] * mp[e]);
    *(u32x4*)&Ap[idx8] = p.v;
  }
  // W swizzles: n = (nl&3)*1024 + wb*4 + (nl>>2), 8 contiguous k
  if (t < 524288u) {
    const unsigned l   = (idx8 >> 3) & 63u;
    const unsigned kcw = (idx8 >> 9) & 31u;
    const unsigned wb  = idx8 >> 14;
    const unsigned nl  = l & 15u;
    const unsigned n   = (nl & 3u) * 1024u + wb * 4u + (nl >> 2);
    const unsigned k   = kcw * 32u + (l >> 4) * 8u;
    const float* wip = &Wih[n * 1024u + k];
    const float* whp = &Whh[n * 1024u + k];
    Pack8 pi, ph;
    #pragma unroll
    for (int e = 0; e < 8; ++e) { pi.o[e] = f2bf(wip[e]); ph.o[e] = f2bf(whp[e]); }
    *(u32x4*)&Wihp[idx8] = pi.v;
    *(u32x4*)&Whhp[idx8] = ph.v;
  }
  // mh slot 0 = bf16(h0 * mask_h); c init (fallback path)
  if (t < 8192u) {
    const unsigned l   = (idx8 >> 3) & 63u;
    const unsigned kwg = (idx8 >> 9) & 31u;
    const unsigned m   = idx8 >> 14;
    const unsigned b   = m * 16u + (l & 15u);
    const unsigned k   = kwg * 32u + (l >> 4) * 8u;
    const float* hp = &h0[b * 1024u + k];
    const float* mp = &mask_h[b * 1024u + k];
    Pack8 p;
    #pragma unroll
    for (int e = 0; e < 8; ++e) p.o[e] = f2bf(hp[e] * mp[e]);
    *(u32x4*)&mhp0[idx8] = p.v;
    *(f32x4*)&c[idx8]     = *(const f32x4*)&c0[idx8];
    *(f32x4*)&c[idx8 + 4] = *(const f32x4*)&c0[idx8 + 4];
  }
  if (t < 512u) {
    #pragma unroll
    for (int e = 0; e < 8; ++e) bias[idx8 + e] = bih[idx8 + e] + bhh[idx8 + e];
  }
  if (persist && t < 256u) flags[t] = 0u;
}

// ---------------------------------------------------------------------------
// Persistent recurrence kernel: 256 blocks x 512 threads, all 256 steps.
// Block (rg = bk>>6, cg = bk&63) owns rows [rg*16, rg*16+16) x h-cols
// [cg*16, cg*16+16) (x4 gates). Wave w owns K-slice [w*128, (w+1)*128),
// which depends on producers (rg, 8w..8w+7) only -> per-wave flag poll.
// ---------------------------------------------------------------------------
__global__ __launch_bounds__(512) void lstm_persist(
    const u16* __restrict__ Ap, const u16* __restrict__ Wihp,
    const u16* __restrict__ Whhp, const float* __restrict__ bias,
    const float* __restrict__ c0, const float* __restrict__ mask_h,
    u16* __restrict__ mh_seq,
    u32* __restrict__ flags, float* __restrict__ out)
{
  __shared__ f32x4 lds[8][4][64];   // [ww][nt][l] 32 KB
  __shared__ u32 cnt;               // epilogue arrive counter

  const int tid = threadIdx.x;
  const int w   = tid >> 6;       // K-slice 0..7
  const int l   = tid & 63;
  const int bk  = blockIdx.x;
  const int rg  = bk >> 6;        // row-group 0..3 (16 batch rows)
  const int cg  = bk & 63;        // col-group 0..63 (16 h-cols)

  const bf16x8* WHV = (const bf16x8*)Whhp;
  const bf16x8* WIV = (const bf16x8*)Wihp;
  const bf16x8* ApV = (const bf16x8*)Ap;

  // Weights resident in registers for the whole sequence: 4 n-tiles x 4 kw.
  bf16x8 wh[4][4], wi[4][4];
  #pragma unroll
  for (int nt = 0; nt < 4; ++nt)
    #pragma unroll
    for (int kw = 0; kw < 4; ++kw) {
      wh[nt][kw] = WHV[((cg * 4 + nt) * 32 + w * 4 + kw) * 64 + l];
      wi[nt][kw] = WIV[((cg * 4 + nt) * 32 + w * 4 + kw) * 64 + l];
    }

  const int nl     = l & 15;
  const int quad   = l >> 4;
  const int g_role = nl & 3;
  const int jh     = nl >> 2;

  // Epilogue assignment: wave w handles n-tile (w&3), rows r in {rb, rb+1}.
  const int nt_e  = w & 3;
  const int rb    = (w >> 2) * 2;
  const int col_h = cg * 16 + nt_e * 4 + jh;
  const float bias_reg = bias[g_role * 1024 + col_h];
  float c_reg[2], mask_reg[2];
  #pragma unroll
  for (int rl = 0; rl < 2; ++rl) {
    const int row = rg * 16 + quad * 4 + rb + rl;
    c_reg[rl]    = c0[row * 1024 + col_h];
    mask_reg[rl] = mask_h[row * 1024 + col_h];
  }

  // mh store base (u16 units) for nl==0 lanes: fragment (m=rg, kwg=cg>>1),
  // l_t = ((cg&1)*2 + (nt_e>>1))*16 + row16, e = (nt_e&1)*4 + jh.
  const int mh_u16_base =
      ((rg * 32 + (cg >> 1)) * 64 + ((cg & 1) * 2 + (nt_e >> 1)) * 16 + quad * 4) * 8
      + (nt_e & 1) * 4;   // + (rb+rl)*8 per row

  // Per-wave poll address: this wave's 8 producers are (rg, 8w..8w+7).
  const u32 poll_off = (u32)((rg * 64 + w * 8 + (l & 7)) * 4);

  if (tid == 0) cnt = 0u;
  __syncthreads();

  for (int s = 0; s < SEQ; ++s) {
    const u16* mi = mh_seq + (size_t)s * 65536;        // step-s input
    u16*       mo = mh_seq + (size_t)(s + 1) * 65536;  // step-s output

    // ---- 1. x-projection (no cross-step dependency; overlaps producers).
    f32x4 acc[4];
    #pragma unroll
    for (int nt = 0; nt < 4; ++nt) acc[nt] = (f32x4){0.f, 0.f, 0.f, 0.f};
    #pragma unroll
    for (int kw = 0; kw < 4; ++kw) {
      bf16x8 a = ApV[((s * 4 + rg) * 32 + w * 4 + kw) * 64 + l];
      #pragma unroll
      for (int nt = 0; nt < 4; ++nt)
        acc[nt] = __builtin_amdgcn_mfma_f32_16x16x32_bf16(a, wi[nt][kw], acc[nt], 0, 0, 0);
    }

    // ---- 2. per-wave gate: poll ONLY this wave's 8 producer flags.
    // One dword per lane (dup mod 8 -> single coalesced 32B transaction).
    if (s > 0) {
      const u32 target = (u32)s;
      int spins = 0;
      for (;;) {
        u32 f;
        asm volatile("global_load_dword %0, %1, %2 sc0 sc1\n\t"
                     "s_waitcnt vmcnt(0)"
                     : "=v"(f) : "v"(poll_off), "s"(flags) : "memory");
        if (__all(f >= target)) break;
        if (++spins > (1 << 15)) break;   // failsafe: never hang the queue
        __builtin_amdgcn_s_sleep(1);
      }
    }

    // ---- 3. recurrent part: 4 bypass fragments (rows rg*16..+16, own kwg).
    union { u32x4 r; bf16x8 v; } hf[4];
    #pragma unroll
    for (int kw = 0; kw < 4; ++kw) {
      const u32 off = (u32)(((rg * 32 + w * 4 + kw) * 64 + l) * 16);
      asm volatile("global_load_dwordx4 %0, %1, %2 sc0 sc1"
                   : "=v"(hf[kw].r) : "v"(off), "s"(mi) : "memory");
    }
    asm volatile("s_waitcnt vmcnt(0)" ::: "memory");
    __builtin_amdgcn_sched_barrier(0);   // rule #18: pin MFMAs after the wait
    #pragma unroll
    for (int kw = 0; kw < 4; ++kw)
      #pragma unroll
      for (int nt = 0; nt < 4; ++nt)
        acc[nt] = __builtin_amdgcn_mfma_f32_16x16x32_bf16(hf[kw].v, wh[nt][kw], acc[nt], 0, 0, 0);

    #pragma unroll
    for (int nt = 0; nt < 4; ++nt) lds[w][nt][l] = acc[nt];
    __syncthreads();   // #1: LDS writes -> reduce (syncs all waves' arrivals)

    // ---- 4. epilogue: all 8 waves; wave w reduces n-tile nt_e, rows rb,rb+1.
    f32x4 t = lds[0][nt_e][l];
    #pragma unroll
    for (int ww = 1; ww < 8; ++ww) t += lds[ww][nt_e][l];

    f32x4 ho_s[2];
    f32x4 co_s[2];
    #pragma unroll
    for (int rl = 0; rl < 2; ++rl) {
      const int r = rb + rl;
      const float gp = t[r] + bias_reg;
      const float v1 = __shfl_xor(gp, 1, 64);
      const float v2 = __shfl_xor(gp, 2, 64);
      const float v3 = __shfl_xor(gp, 3, 64);
      const float ig = pick4(g_role,     gp, v1, v2, v3);
      const float fg = pick4(g_role ^ 1, gp, v1, v2, v3);
      const float gg = pick4(g_role ^ 2, gp, v1, v2, v3);
      const float og = pick4(g_role ^ 3, gp, v1, v2, v3);
      const float iv = sigm(ig);
      const float fv = sigm(fg);
      const float gv = tanh_fast(gg);
      const float ov = sigm(og);
      const float cn = fv * c_reg[rl] + iv * gv;
      c_reg[rl] = cn;
      const float hn = ov * tanh_fast(cn);
      const float mv = hn * mask_reg[rl];

      // gather the n-tile's 4 h-cols (jh) into the nl==0 lanes
      const float h1 = __shfl_xor(hn, 4, 64);
      const float h2 = __shfl_xor(hn, 8, 64);
      const float h3 = __shfl_xor(hn, 12, 64);
      const float m1 = __shfl_xor(mv, 4, 64);
      const float m2 = __shfl_xor(mv, 8, 64);
      const float m3 = __shfl_xor(mv, 12, 64);
      ho_s[rl] = (f32x4){hn, h1, h2, h3};
      if (s == SEQ - 1) {
        const float cn1 = __shfl_xor(cn, 4, 64);
        const float cn2 = __shfl_xor(cn, 8, 64);
        const float cn3 = __shfl_xor(cn, 12, 64);
        co_s[rl] = (f32x4){cn, cn1, cn2, cn3};
      }
      if (nl == 0) {
        // mh store FIRST (the only store other blocks wait on) — agent
        // scope write-through so it reaches the MALL before the flag.
        const u64 pk = (u64)f2bf(mv) | ((u64)f2bf(m1) << 16)
                     | ((u64)f2bf(m2) << 32) | ((u64)f2bf(m3) << 48);
        __hip_atomic_store((u64*)&mo[mh_u16_base + r * 8], pk,
                           __ATOMIC_RELAXED, __HIP_MEMORY_SCOPE_AGENT);
      }
    }
    // drain mh stores, arrive; LAST wave releases the flag. Out stores after.
    asm volatile("s_waitcnt vmcnt(0)" ::: "memory");
    u32 old = 0u;
    if (l == 0)
      old = __hip_atomic_fetch_add(&cnt, 1u, __ATOMIC_RELAXED, __HIP_MEMORY_SCOPE_WORKGROUP);
    if (l == 0 && old == 7u) {
      __hip_atomic_store(&cnt, 0u, __ATOMIC_RELAXED, __HIP_MEMORY_SCOPE_WORKGROUP);
      if (s < SEQ - 1) {
        u32 val  = (u32)(s + 1);
        u32 voff = (u32)(bk * 4);
        asm volatile("global_store_dword %0, %1, %2 sc0 sc1"
                     :: "v"(voff), "v"(val), "s"(flags) : "memory");
      }
    }
    if (nl == 0) {
      #pragma unroll
      for (int rl = 0; rl < 2; ++rl) {
        const int row = rg * 16 + quad * 4 + rb + rl;
        *(f32x4*)&out[((size_t)s * 64 + row) * 1024 + cg * 16 + nt_e * 4] = ho_s[rl];
        if (s == SEQ - 1) {
          *(f32x4*)&out[16777216 + row * 1024 + cg * 16 + nt_e * 4] = ho_s[rl];         // h_n
          *(f32x4*)&out[16777216 + 65536 + row * 1024 + cg * 16 + nt_e * 4] = co_s[rl]; // c_n
        }
      }
    }
    __syncthreads();   // #2: WAR protection for lds + cnt + step advance
  }
}

// ---------------------------------------------------------------------------
// Fallback per-step kernel (R3, unchanged): used only when ws is too small.
// ---------------------------------------------------------------------------
__global__ __launch_bounds__(256) void lstm_step(
    const u16* __restrict__ Ap,
    const u16* __restrict__ Wihp,
    const u16* __restrict__ Whhp,
    const _Float16* __restrict__ xg,  // null => fold x-GEMM
    const float* __restrict__ bias,
    const u16* __restrict__ mh_in, u16* __restrict__ mh_out,
    float* __restrict__ c, const float* __restrict__ mask_h,
    float* __restrict__ out, int s)
{
  __shared__ f32x4 lds[4][4][64];   // [w][m][l] 16 KB

  const int tid = threadIdx.x;
  const int w   = tid >> 6;      // K-slice
  const int l   = tid & 63;
  const int bk  = blockIdx.x;    // 4 h-cols

  const bf16x8* mb = (const bf16x8*)mh_in;
  const bf16x8* WH = (const bf16x8*)Whhp;

  f32x4 acc[4] = { {0,0,0,0}, {0,0,0,0}, {0,0,0,0}, {0,0,0,0} };

  #pragma unroll 2
  for (int kw = 0; kw < 8; ++kw) {
    bf16x8 b = WH[(bk * 32 + w * 8 + kw) * 64 + l];
    #pragma unroll
    for (int m = 0; m < 4; ++m) {
      bf16x8 a = mb[(m * 32 + w * 8 + kw) * 64 + l];
      acc[m] = __builtin_amdgcn_mfma_f32_16x16x32_bf16(a, b, acc[m], 0, 0, 0);
    }
  }
  if (xg == nullptr) {   // fold x-projection
    const bf16x8* ApV = (const bf16x8*)Ap;
    const bf16x8* WI  = (const bf16x8*)Wihp;
    #pragma unroll 2
    for (int kw = 0; kw < 8; ++kw) {
      bf16x8 b = WI[(bk * 32 + w * 8 + kw) * 64 + l];
      #pragma unroll
      for (int m = 0; m < 4; ++m) {
        bf16x8 a = ApV[((s * 4 + m) * 32 + w * 8 + kw) * 64 + l];
        acc[m] = __builtin_amdgcn_mfma_f32_16x16x32_bf16(a, b, acc[m], 0, 0, 0);
      }
    }
  }
  #pragma unroll
  for (int m = 0; m < 4; ++m) lds[w][m][l] = acc[m];
  __syncthreads();

  f32x4 t = lds[0][w][l];
  #pragma unroll
  for (int ww = 1; ww < 4; ++ww) t += lds[ww][w][l];

  const int nl     = l & 15;
  const int quad   = l >> 4;
  const int g_role = nl & 3;
  const int jh     = nl >> 2;
  const int col_h  = bk * 4 + jh;

  if (xg != nullptr) {
    f16x4 xv = *(const f16x4*)&xg[((((size_t)s * 256 + bk) * 4 + w) * 64 + l) * 4];
    #pragma unroll
    for (int r = 0; r < 4; ++r) t[r] += (float)xv[r];
  }
  const float bias_reg = bias[g_role * 1024 + col_h];
  const int kwg = col_h >> 5;
  const int lp  = ((col_h >> 3) & 3) * 16;

  #pragma unroll
  for (int r = 0; r < 4; ++r) {
    const int b_row = w * 16 + quad * 4 + r;
    const float gp = t[r] + bias_reg;
    const float v1 = __shfl_xor(gp, 1, 64);
    const float v2 = __shfl_xor(gp, 2, 64);
    const float v3 = __shfl_xor(gp, 3, 64);
    const float ig = pick4(g_role,     gp, v1, v2, v3);
    const float fg = pick4(g_role ^ 1, gp, v1, v2, v3);
    const float gg = pick4(g_role ^ 2, gp, v1, v2, v3);
    const float og = pick4(g_role ^ 3, gp, v1, v2, v3);
    const float iv = sigm(ig);
    const float fv = sigm(fg);
    const float gv = tanh_fast(gg);
    const float ov = sigm(og);
    const float cold = c[b_row * 1024 + col_h];
    const float cn = fv * cold + iv * gv;
    const float hn = ov * tanh_fast(cn);
    if (g_role == 0) {
      c[b_row * 1024 + col_h] = cn;
      out[((size_t)s * 64 + b_row) * 1024 + col_h] = hn;
      mh_out[((w * 32 + kwg) * 64 + (lp + (b_row & 15))) * 8 + (col_h & 7)] =
          f2bf(hn * mask_h[b_row * 1024 + col_h]);
      if (s == SEQ - 1) {
        out[16777216 + b_row * 1024 + col_h] = hn;           // h_n
        out[16777216 + 65536 + b_row * 1024 + col_h] = cn;   // c_n
      }
    }
  }
}

extern "C" void kernel_launch(void* const* d_in, const int* in_sizes, int n_in,
                              void* d_out, int out_size, void* d_ws, size_t ws_size,
                              hipStream_t stream)
{
  const float* x      = (const float*)d_in[0];
  const float* h0     = (const float*)d_in[1];
  const float* c0     = (const float*)d_in[2];
  const float* mask_x = (const float*)d_in[3];
  const float* mask_h = (const float*)d_in[4];
  const float* Wih    = (const float*)d_in[5];
  const float* Whh    = (const float*)d_in[6];
  const float* bih    = (const float*)d_in[7];
  const float* bhh    = (const float*)d_in[8];
  float* out = (float*)d_out;

  char* ws = (char*)d_ws;
  u16*   Wihp   = (u16*)(ws + 0);
  u16*   Whhp   = (u16*)(ws + 8388608);
  u16*   Ap     = (u16*)(ws + 16777216);
  u16*   mh0    = (u16*)(ws + 50331648);
  u16*   mh1    = (u16*)(ws + 50462720);
  float* bias   = (float*)(ws + 50593792);
  float* c      = (float*)(ws + 50610176);
  u32*   flags  = (u32*)(ws + 50872320);
  u16*   mh_seq = (u16*)(ws + 50873344);   // 257 x 131072 B, end 84558848
  const bool persist = (ws_size >= (size_t)84558848);

  u16* mh_init = persist ? mh_seq : mh0;   // prep writes the step-0 mh here

  hipLaunchKernelGGL(prep_kernel, dim3(8192), dim3(256), 0, stream,
                     x, h0, c0, mask_x, mask_h, Wih, Whh, bih, bhh,
                     Wihp, Whhp, Ap, mh_init, bias, c, flags, (int)persist);

  if (persist) {
    hipLaunchKernelGGL(lstm_persist, dim3(256), dim3(512), 0, stream,
                       Ap, Wihp, Whhp, bias, c0, mask_h, mh_seq, flags, out);
  } else {
    for (int s = 0; s < SEQ; ++s) {
      const u16* mi = (s & 1) ? mh1 : mh0;
      u16*       mo = (s & 1) ? mh0 : mh1;
      hipLaunchKernelGGL(lstm_step, dim3(256), dim3(256), 0, stream,
                         Ap, Wihp, Whhp, (const _Float16*)nullptr, bias, mi, mo,
                         c, mask_h, out, s);
    }
  }
}